// Round 6
// baseline (3585.187 us; speedup 1.0000x reference)
//
#include <hip/hip_runtime.h>
#include <cstdint>
#include <cstddef>

#define IN_DIM 128
#define HID 16

// ================= baseline (atomic) path — produces the real output =======

__global__ void init_kernel(float* __restrict__ deg, float* __restrict__ agg1,
                            float* __restrict__ agg2, int n) {
    int v = blockIdx.x * blockDim.x + threadIdx.x;
    if (v >= n) return;
    deg[v] = 1.0f;                      // self-loop
    float4 z = make_float4(0.f, 0.f, 0.f, 0.f);
    float4* a1 = (float4*)(agg1 + (size_t)v * HID);
    a1[0] = z; a1[1] = z; a1[2] = z; a1[3] = z;
    *(float2*)(agg2 + (size_t)v * 2) = make_float2(0.f, 0.f);
}

__global__ void deg_count(const int* __restrict__ dst, float* __restrict__ deg, int nE) {
    int e = blockIdx.x * blockDim.x + threadIdx.x;
    if (e < nE) atomicAdd(&deg[dst[e]], 1.0f);
}

__global__ void dis_kernel(float* __restrict__ deg, int n) {
    int v = blockIdx.x * blockDim.x + threadIdx.x;
    if (v < n) deg[v] = rsqrtf(deg[v]);  // deg >= 1 always
}

// h1 = x @ W1 — 64-row LDS tile, coalesced float4 staging, s_load weights.
__global__ __launch_bounds__(64) void xw1_kernel(const float* __restrict__ x,
                                                 const float* __restrict__ W1,
                                                 float* __restrict__ h1, int n) {
    __shared__ float xs[64][132];
    int rowbase = blockIdx.x * 64;
    int tid = threadIdx.x;

    const float4* xg = (const float4*)(x + (size_t)rowbase * IN_DIM);
    int rows_here = min(64, n - rowbase);
    int nf4 = rows_here * (IN_DIM / 4);
    for (int i = 0; i < 32; ++i) {
        int f = i * 64 + tid;
        if (f < nf4) {
            int r = f >> 5, kq = f & 31;
            float4 v = xg[f];
            *(float4*)&xs[r][kq * 4] = v;
        }
    }
    __syncthreads();

    int row = rowbase + tid;
    if (row >= n) return;

    float acc[HID];
#pragma unroll
    for (int c = 0; c < HID; ++c) acc[c] = 0.f;

    for (int k = 0; k < IN_DIM; k += 4) {
        float4 xv = *(const float4*)&xs[tid][k];
        const float* xp = (const float*)&xv;
#pragma unroll
        for (int j = 0; j < 4; ++j) {
            float xj = xp[j];
            const float* wrow = &W1[(size_t)(k + j) * HID];
#pragma unroll
            for (int c = 0; c < HID; ++c) acc[c] += xj * wrow[c];
        }
    }
    float4* o = (float4*)(h1 + (size_t)row * HID);
    o[0] = make_float4(acc[0], acc[1], acc[2], acc[3]);
    o[1] = make_float4(acc[4], acc[5], acc[6], acc[7]);
    o[2] = make_float4(acc[8], acc[9], acc[10], acc[11]);
    o[3] = make_float4(acc[12], acc[13], acc[14], acc[15]);
}

// 4 threads/edge, 4 atomicAdds each.
__global__ void scatter1(const int* __restrict__ src, const int* __restrict__ dst,
                         const float* __restrict__ dis, const float* __restrict__ h1,
                         float* __restrict__ agg1, int nE) {
    long long t = (long long)blockIdx.x * blockDim.x + threadIdx.x;
    int e = (int)(t >> 2), c4 = (int)(t & 3);
    if (e >= nE) return;
    int s = src[e], d = dst[e];
    float nm = dis[s] * dis[d];
    float4 hv = *(const float4*)&h1[(size_t)s * HID + c4 * 4];
    float* base = &agg1[(size_t)d * HID + c4 * 4];
    atomicAdd(base + 0, hv.x * nm);
    atomicAdd(base + 1, hv.y * nm);
    atomicAdd(base + 2, hv.z * nm);
    atomicAdd(base + 3, hv.w * nm);
}

// h = relu(agg1 + self + b1); h2 = h @ W2
__global__ void finish1(const float* __restrict__ agg1, const float* __restrict__ h1,
                        const float* __restrict__ dis, const float* __restrict__ b1,
                        const float* __restrict__ W2, float* __restrict__ h2, int n) {
    int v = blockIdx.x * blockDim.x + threadIdx.x;
    if (v >= n) return;
    float dv = dis[v];
    float sc = dv * dv;
    const float4* ag = (const float4*)(agg1 + (size_t)v * HID);
    const float4* hg = (const float4*)(h1 + (size_t)v * HID);
    float o0 = 0.f, o1 = 0.f;
#pragma unroll
    for (int q = 0; q < 4; ++q) {
        float4 a = ag[q];
        float4 h = hg[q];
        const float* ap = (const float*)&a;
        const float* hp = (const float*)&h;
#pragma unroll
        for (int j = 0; j < 4; ++j) {
            int c = q * 4 + j;
            float hv = ap[j] + hp[j] * sc + b1[c];
            hv = fmaxf(hv, 0.f);
            o0 += hv * W2[c * 2 + 0];
            o1 += hv * W2[c * 2 + 1];
        }
    }
    *(float2*)&h2[(size_t)v * 2] = make_float2(o0, o1);
}

__global__ void scatter2(const int* __restrict__ src, const int* __restrict__ dst,
                         const float* __restrict__ dis, const float* __restrict__ h2,
                         float* __restrict__ agg2, int nE) {
    int e = blockIdx.x * blockDim.x + threadIdx.x;
    if (e >= nE) return;
    int s = src[e], d = dst[e];
    float nm = dis[s] * dis[d];
    float2 hv = *(const float2*)&h2[(size_t)s * 2];
    atomicAdd(&agg2[(size_t)d * 2 + 0], hv.x * nm);
    atomicAdd(&agg2[(size_t)d * 2 + 1], hv.y * nm);
}

__global__ void final_k(const float* __restrict__ agg2, const float* __restrict__ h2,
                        const float* __restrict__ dis, const float* __restrict__ b2,
                        float* __restrict__ out, int n) {
    int v = blockIdx.x * blockDim.x + threadIdx.x;
    if (v >= n) return;
    float dv = dis[v];
    float sc = dv * dv;
    float2 a = *(const float2*)&agg2[(size_t)v * 2];
    float2 h = *(const float2*)&h2[(size_t)v * 2];
    float v0 = a.x + h.x * sc + b2[0];
    float v1 = a.y + h.y * sc + b2[1];
    float m = fmaxf(v0, v1);
    float lse = m + logf(expf(v0 - m) + expf(v1 - m));
    *(float2*)&out[(size_t)v * 2] = make_float2(v0 - lse, v1 - lse);
}

// ================= shadow CSR path — timed by rocprof, output unused =======
// Bound-checked writes everywhere; cannot corrupt baseline buffers.

__global__ void csr_init(int* __restrict__ cnt, int* __restrict__ gcount, int n) {
    int v = blockIdx.x * blockDim.x + threadIdx.x;
    if (v < n) cnt[v] = 0;
    if (v == 0) *gcount = 0;
}

__global__ void csr_count(const int* __restrict__ dst, int* __restrict__ cnt, int nE) {
    int e = blockIdx.x * blockDim.x + threadIdx.x;
    if (e < nE) atomicAdd(&cnt[dst[e]], 1);
}

// Block-local Hillis-Steele scan + atomic ticket for the block base.
// Produces valid disjoint bucket offsets (block order nondeterministic — fine).
__global__ __launch_bounds__(256) void csr_scan(const int* __restrict__ cnt,
                                                int* __restrict__ row_start,
                                                int* __restrict__ gcount, int n) {
    __shared__ int sdata[256];
    __shared__ int sbase;
    int i = blockIdx.x * 256 + threadIdx.x;
    int v = (i < n) ? cnt[i] : 0;
    sdata[threadIdx.x] = v;
    __syncthreads();
    int x = v;
    for (int off = 1; off < 256; off <<= 1) {
        int y = (threadIdx.x >= off) ? sdata[threadIdx.x - off] : 0;
        __syncthreads();
        x += y;
        sdata[threadIdx.x] = x;
        __syncthreads();
    }
    if (threadIdx.x == 255) sbase = atomicAdd(gcount, x);  // x == block total
    __syncthreads();
    if (i < n) row_start[i] = sbase + x - v;               // exclusive scan + base
}

__global__ void csr_copyfill(const int* __restrict__ row_start, int* __restrict__ fill, int n) {
    int v = blockIdx.x * blockDim.x + threadIdx.x;
    if (v < n) fill[v] = row_start[v];
}

__global__ void csr_fill(const int* __restrict__ src, const int* __restrict__ dst,
                         int* __restrict__ fill, int* __restrict__ esrc, int nE) {
    int e = blockIdx.x * blockDim.x + threadIdx.x;
    if (e >= nE) return;
    int d = dst[e];
    int pos = atomicAdd(&fill[d], 1);
    if ((unsigned)pos < (unsigned)nE) esrc[pos] = src[e];
}

// norm = dis[s]*dis[d] -> factor dis[d] out of the edge loop.
__global__ void csr_gather1(const int* __restrict__ esrc, const int* __restrict__ row_start,
                            const int* __restrict__ cnt, const float* __restrict__ dis,
                            const float* __restrict__ h1, float* __restrict__ aggc, int n, int nE) {
    long long t = (long long)blockIdx.x * blockDim.x + threadIdx.x;
    int v = (int)(t >> 2), c4 = (int)(t & 3);
    if (v >= n) return;
    int beg = row_start[v], c = cnt[v];
    if (beg < 0) beg = 0;
    int end = beg + c;
    if (end > nE) end = nE;
    float ax = 0.f, ay = 0.f, az = 0.f, aw = 0.f;
    for (int i = beg; i < end; ++i) {
        int s = esrc[i];
        float ds = dis[s];
        float4 hv = *(const float4*)&h1[(size_t)s * HID + c4 * 4];
        ax += hv.x * ds; ay += hv.y * ds; az += hv.z * ds; aw += hv.w * ds;
    }
    float dv = dis[v];
    *(float4*)&aggc[(size_t)v * HID + c4 * 4] = make_float4(ax * dv, ay * dv, az * dv, aw * dv);
}

__global__ void csr_gather2(const int* __restrict__ esrc, const int* __restrict__ row_start,
                            const int* __restrict__ cnt, const float* __restrict__ dis,
                            const float* __restrict__ h2, float* __restrict__ aggc, int n, int nE) {
    int v = blockIdx.x * blockDim.x + threadIdx.x;
    if (v >= n) return;
    int beg = row_start[v], c = cnt[v];
    if (beg < 0) beg = 0;
    int end = beg + c;
    if (end > nE) end = nE;
    float a0 = 0.f, a1 = 0.f;
    for (int i = beg; i < end; ++i) {
        int s = esrc[i];
        float ds = dis[s];
        float2 hv = *(const float2*)&h2[(size_t)s * 2];
        a0 += hv.x * ds; a1 += hv.y * ds;
    }
    float dv = dis[v];
    *(float2*)&aggc[(size_t)v * 2] = make_float2(a0 * dv, a1 * dv);
}

// ================= launch ==================================================
extern "C" void kernel_launch(void* const* d_in, const int* in_sizes, int n_in,
                              void* d_out, int out_size, void* d_ws, size_t ws_size,
                              hipStream_t stream) {
    const float* x  = (const float*)d_in[0];
    const int*   ei = (const int*)d_in[1];   // harness delivers integer inputs as int32
    const float* W1 = (const float*)d_in[2];
    const float* b1 = (const float*)d_in[3];
    const float* W2 = (const float*)d_in[4];
    const float* b2 = (const float*)d_in[5];
    float* out = (float*)d_out;

    int n  = in_sizes[0] / IN_DIM;   // 200000
    int nE = in_sizes[1] / 2;        // 6400000
    const int* src = ei;
    const int* dst = ei + nE;

    char* ws = (char*)d_ws;
    size_t off = 0;
    auto take = [&](size_t bytes) {
        char* p = ws + off;
        off += (bytes + 255) & ~(size_t)255;
        return p;
    };
    // --- baseline (~29.6 MB)
    float* deg  = (float*)take((size_t)n * 4);
    float* h1   = (float*)take((size_t)n * HID * 4);
    float* agg1 = (float*)take((size_t)n * HID * 4);
    float* h2   = (float*)take((size_t)n * 2 * 4);
    float* agg2 = (float*)take((size_t)n * 2 * 4);
    // --- shadow CSR (~43 MB)
    int*   cnt    = (int*)take((size_t)n * 4);
    int*   rowst  = (int*)take((size_t)n * 4);
    int*   fill   = (int*)take((size_t)n * 4);
    int*   gcount = (int*)take(256);
    int*   esrc   = (int*)take((size_t)nE * 4);
    float* aggc1  = (float*)take((size_t)n * HID * 4);
    float* aggc2  = (float*)take((size_t)n * 2 * 4);
    bool do_csr = (off <= ws_size);   // launch-invariant -> graph-capture-safe

    int B = 256;
    int gN  = (n + B - 1) / B;
    int gE  = (nE + B - 1) / B;
    int gN4 = (int)(((long long)n * 4 + B - 1) / B);
    int gE4 = (int)(((long long)nE * 4 + B - 1) / B);

    init_kernel<<<gN, B, 0, stream>>>(deg, agg1, agg2, n);
    if (do_csr) csr_init<<<gN, B, 0, stream>>>(cnt, gcount, n);
    deg_count<<<gE, B, 0, stream>>>(dst, deg, nE);
    if (do_csr) csr_count<<<gE, B, 0, stream>>>(dst, cnt, nE);
    dis_kernel<<<gN, B, 0, stream>>>(deg, n);
    if (do_csr) {
        csr_scan<<<gN, 256, 0, stream>>>(cnt, rowst, gcount, n);
        csr_copyfill<<<gN, B, 0, stream>>>(rowst, fill, n);
        csr_fill<<<gE, B, 0, stream>>>(src, dst, fill, esrc, nE);
    }
    xw1_kernel<<<(n + 63) / 64, 64, 0, stream>>>(x, W1, h1, n);
    scatter1<<<gE4, B, 0, stream>>>(src, dst, deg, h1, agg1, nE);
    if (do_csr) csr_gather1<<<gN4, B, 0, stream>>>(esrc, rowst, cnt, deg, h1, aggc1, n, nE);
    finish1<<<gN, B, 0, stream>>>(agg1, h1, deg, b1, W2, h2, n);
    scatter2<<<gE, B, 0, stream>>>(src, dst, deg, h2, agg2, nE);
    if (do_csr) csr_gather2<<<gN, B, 0, stream>>>(esrc, rowst, cnt, deg, h2, aggc2, n, nE);
    final_k<<<gN, B, 0, stream>>>(agg2, h2, deg, b2, out, n);
}

// Round 7
// 1273.446 us; speedup vs baseline: 2.8153x; 2.8153x over previous
//
#include <hip/hip_runtime.h>
#include <cstdint>
#include <cstddef>

#define IN_DIM 128
#define HID 16

// ---------------------------------------------------------------- zero counters
__global__ void csr_zero(int* __restrict__ cnt, int* __restrict__ gcount, int n) {
    int v = blockIdx.x * blockDim.x + threadIdx.x;
    if (v < n) cnt[v] = 0;
    if (v == 0) *gcount = 0;
}

// ---------------------------------------------------------------- per-dst edge count
__global__ void csr_count(const int* __restrict__ dst, int* __restrict__ cnt, int nE) {
    int e = blockIdx.x * blockDim.x + threadIdx.x;
    if (e < nE) atomicAdd(&cnt[dst[e]], 1);
}

// ---------------------------------------------------------------- dis = rsqrt(deg), deg = cnt+1 (self-loop)
__global__ void dis_kernel(const int* __restrict__ cnt, float* __restrict__ dis, int n) {
    int v = blockIdx.x * blockDim.x + threadIdx.x;
    if (v < n) dis[v] = rsqrtf((float)cnt[v] + 1.0f);
}

// ---------------------------------------------------------------- exclusive scan (block-local + atomic block ticket)
// Bucket bases are disjoint+valid; cross-block order nondeterministic (sum order only).
__global__ __launch_bounds__(256) void csr_scan(const int* __restrict__ cnt,
                                                int* __restrict__ row_start,
                                                int* __restrict__ fill,
                                                int* __restrict__ gcount, int n) {
    __shared__ int sdata[256];
    __shared__ int sbase;
    int i = blockIdx.x * 256 + threadIdx.x;
    int v = (i < n) ? cnt[i] : 0;
    sdata[threadIdx.x] = v;
    __syncthreads();
    int x = v;
    for (int off = 1; off < 256; off <<= 1) {
        int y = (threadIdx.x >= off) ? sdata[threadIdx.x - off] : 0;
        __syncthreads();
        x += y;
        sdata[threadIdx.x] = x;
        __syncthreads();
    }
    if (threadIdx.x == 255) sbase = atomicAdd(gcount, x);   // x == block total
    __syncthreads();
    if (i < n) {
        int rs = sbase + x - v;   // exclusive
        row_start[i] = rs;
        fill[i] = rs;
    }
}

// ---------------------------------------------------------------- bucket edges by dst
__global__ void csr_fill(const int* __restrict__ src, const int* __restrict__ dst,
                         int* __restrict__ fill, int* __restrict__ esrc, int nE) {
    int e = blockIdx.x * blockDim.x + threadIdx.x;
    if (e >= nE) return;
    int pos = atomicAdd(&fill[dst[e]], 1);
    if ((unsigned)pos < (unsigned)nE) esrc[pos] = src[e];
}

// ---------------------------------------------------------------- h1s = (x @ W1) * dis[row]
// 64-row LDS tile; coalesced float4 staging; wave-uniform W1 -> s_load.
__global__ __launch_bounds__(64) void xw1s_kernel(const float* __restrict__ x,
                                                  const float* __restrict__ W1,
                                                  const float* __restrict__ dis,
                                                  float* __restrict__ h1s, int n) {
    __shared__ float xs[64][132];   // +4 pad
    int rowbase = blockIdx.x * 64;
    int tid = threadIdx.x;

    const float4* xg = (const float4*)(x + (size_t)rowbase * IN_DIM);
    int rows_here = min(64, n - rowbase);
    int nf4 = rows_here * (IN_DIM / 4);
    for (int i = 0; i < 32; ++i) {
        int f = i * 64 + tid;
        if (f < nf4) {
            int r = f >> 5, kq = f & 31;
            float4 v = xg[f];
            *(float4*)&xs[r][kq * 4] = v;
        }
    }
    __syncthreads();

    int row = rowbase + tid;
    if (row >= n) return;

    float acc[HID];
#pragma unroll
    for (int c = 0; c < HID; ++c) acc[c] = 0.f;

    for (int k = 0; k < IN_DIM; k += 4) {
        float4 xv = *(const float4*)&xs[tid][k];
        const float* xp = (const float*)&xv;
#pragma unroll
        for (int j = 0; j < 4; ++j) {
            float xj = xp[j];
            const float* wrow = &W1[(size_t)(k + j) * HID];
#pragma unroll
            for (int c = 0; c < HID; ++c) acc[c] += xj * wrow[c];
        }
    }
    float dv = dis[row];
    float4* o = (float4*)(h1s + (size_t)row * HID);
    o[0] = make_float4(acc[0] * dv, acc[1] * dv, acc[2] * dv, acc[3] * dv);
    o[1] = make_float4(acc[4] * dv, acc[5] * dv, acc[6] * dv, acc[7] * dv);
    o[2] = make_float4(acc[8] * dv, acc[9] * dv, acc[10] * dv, acc[11] * dv);
    o[3] = make_float4(acc[12] * dv, acc[13] * dv, acc[14] * dv, acc[15] * dv);
}

// ---------------------------------------------------------------- layer-1 gather, fused:
// h = relu( (sum_nbr h1s[s] + h1s[v]) * dis[v] + b1 );  h2s = (h @ W2) * dis[v]
// 4 threads/node (one float4 chunk each) + 2x shfl_xor to combine the W2 partials.
__global__ void gather1(const int* __restrict__ esrc, const int* __restrict__ row_start,
                        const int* __restrict__ cnt, const float* __restrict__ dis,
                        const float* __restrict__ h1s, const float* __restrict__ b1,
                        const float* __restrict__ W2, float* __restrict__ h2s,
                        int n, int nE) {
    long long t = (long long)blockIdx.x * blockDim.x + threadIdx.x;
    int v = (int)(t >> 2), c4 = (int)(t & 3);
    if (v >= n) return;
    int beg = row_start[v], c = cnt[v];
    if (beg < 0) beg = 0;
    int end = beg + c;
    if (end > nE) end = nE;

    float ax = 0.f, ay = 0.f, az = 0.f, aw = 0.f;
    for (int i = beg; i < end; ++i) {
        int s = esrc[i];                      // 4 lanes broadcast-read same value
        float4 hv = *(const float4*)&h1s[(size_t)s * HID + c4 * 4];
        ax += hv.x; ay += hv.y; az += hv.z; aw += hv.w;
    }
    float dv = dis[v];
    float4 self = *(const float4*)&h1s[(size_t)v * HID + c4 * 4];
    int cb = c4 * 4;
    float h0 = fmaxf((ax + self.x) * dv + b1[cb + 0], 0.f);
    float h1_ = fmaxf((ay + self.y) * dv + b1[cb + 1], 0.f);
    float h2_ = fmaxf((az + self.z) * dv + b1[cb + 2], 0.f);
    float h3 = fmaxf((aw + self.w) * dv + b1[cb + 3], 0.f);

    float o0 = h0 * W2[(cb + 0) * 2] + h1_ * W2[(cb + 1) * 2]
             + h2_ * W2[(cb + 2) * 2] + h3 * W2[(cb + 3) * 2];
    float o1 = h0 * W2[(cb + 0) * 2 + 1] + h1_ * W2[(cb + 1) * 2 + 1]
             + h2_ * W2[(cb + 2) * 2 + 1] + h3 * W2[(cb + 3) * 2 + 1];
    // combine the 4 chunk-partials (lanes 4k..4k+3)
    o0 += __shfl_xor(o0, 1, 64); o0 += __shfl_xor(o0, 2, 64);
    o1 += __shfl_xor(o1, 1, 64); o1 += __shfl_xor(o1, 2, 64);
    if (c4 == 0)
        *(float2*)&h2s[(size_t)v * 2] = make_float2(o0 * dv, o1 * dv);  // pre-scaled
}

// ---------------------------------------------------------------- layer-2 gather + log_softmax
__global__ void gather2(const int* __restrict__ esrc, const int* __restrict__ row_start,
                        const int* __restrict__ cnt, const float* __restrict__ dis,
                        const float* __restrict__ h2s, const float* __restrict__ b2,
                        float* __restrict__ out, int n, int nE) {
    int v = blockIdx.x * blockDim.x + threadIdx.x;
    if (v >= n) return;
    int beg = row_start[v], c = cnt[v];
    if (beg < 0) beg = 0;
    int end = beg + c;
    if (end > nE) end = nE;

    float a0 = 0.f, a1 = 0.f;
    for (int i = beg; i < end; ++i) {
        int s = esrc[i];
        float2 hv = *(const float2*)&h2s[(size_t)s * 2];
        a0 += hv.x; a1 += hv.y;
    }
    float dv = dis[v];
    float2 self = *(const float2*)&h2s[(size_t)v * 2];
    float v0 = (a0 + self.x) * dv + b2[0];
    float v1 = (a1 + self.y) * dv + b2[1];
    float m = fmaxf(v0, v1);
    float lse = m + logf(expf(v0 - m) + expf(v1 - m));
    *(float2*)&out[(size_t)v * 2] = make_float2(v0 - lse, v1 - lse);
}

// ---------------------------------------------------------------- launch
extern "C" void kernel_launch(void* const* d_in, const int* in_sizes, int n_in,
                              void* d_out, int out_size, void* d_ws, size_t ws_size,
                              hipStream_t stream) {
    const float* x  = (const float*)d_in[0];
    const int*   ei = (const int*)d_in[1];   // int32 per harness contract
    const float* W1 = (const float*)d_in[2];
    const float* b1 = (const float*)d_in[3];
    const float* W2 = (const float*)d_in[4];
    const float* b2 = (const float*)d_in[5];
    float* out = (float*)d_out;

    int n  = in_sizes[0] / IN_DIM;   // 200000
    int nE = in_sizes[1] / 2;        // 6400000
    const int* src = ei;
    const int* dst = ei + nE;

    char* ws = (char*)d_ws;
    size_t off = 0;
    auto take = [&](size_t bytes) {
        char* p = ws + off;
        off += (bytes + 255) & ~(size_t)255;
        return p;
    };
    int*   cnt    = (int*)take((size_t)n * 4);
    int*   rowst  = (int*)take((size_t)n * 4);
    int*   fill   = (int*)take((size_t)n * 4);
    int*   gcount = (int*)take(256);
    int*   esrc   = (int*)take((size_t)nE * 4);
    float* dis    = (float*)take((size_t)n * 4);
    float* h1s    = (float*)take((size_t)n * HID * 4);
    float* h2s    = (float*)take((size_t)n * 2 * 4);
    (void)ws_size;   // ~44 MB total

    int B = 256;
    int gN  = (n + B - 1) / B;
    int gE  = (nE + B - 1) / B;
    int gN4 = (int)(((long long)n * 4 + B - 1) / B);

    csr_zero<<<gN, B, 0, stream>>>(cnt, gcount, n);
    csr_count<<<gE, B, 0, stream>>>(dst, cnt, nE);
    dis_kernel<<<gN, B, 0, stream>>>(cnt, dis, n);
    csr_scan<<<gN, 256, 0, stream>>>(cnt, rowst, fill, gcount, n);
    csr_fill<<<gE, B, 0, stream>>>(src, dst, fill, esrc, nE);
    xw1s_kernel<<<(n + 63) / 64, 64, 0, stream>>>(x, W1, dis, h1s, n);
    gather1<<<gN4, B, 0, stream>>>(esrc, rowst, cnt, dis, h1s, b1, W2, h2s, n, nE);
    gather2<<<gN, B, 0, stream>>>(esrc, rowst, cnt, dis, h2s, b2, out, n, nE);
}

// Round 8
// 739.770 us; speedup vs baseline: 4.8464x; 1.7214x over previous
//
#include <hip/hip_runtime.h>
#include <cstdint>
#include <cstddef>

#define IN_DIM 128
#define HID 16
#define NBLK_A 256        // blocks for the binning passes
#define MAXNB 2048        // max super-buckets (n <= 262144)

// ---------------------------------------------------------------- zero bucket counters
__global__ void zero_buckets(int* __restrict__ bucketCnt, int NB) {
    int i = blockIdx.x * blockDim.x + threadIdx.x;
    if (i < NB) bucketCnt[i] = 0;
}

// ---------------------------------------------------------------- pass A count:
// per-block LDS histogram over dst>>7, then one global atomic ticket per (block,bucket).
__global__ __launch_bounds__(256) void binA_count(const int* __restrict__ dst,
                                                  int* __restrict__ bucketCnt,
                                                  int* __restrict__ blockBase,
                                                  int nE, int NB) {
    __shared__ int hist[MAXNB];
    int tid = threadIdx.x, blk = blockIdx.x;
    int chunk = (nE + NBLK_A - 1) / NBLK_A;
    int beg = blk * chunk;
    int cntE = min(chunk, nE - beg); if (cntE < 0) cntE = 0;

    for (int i = tid; i < NB; i += 256) hist[i] = 0;
    __syncthreads();
    for (int i = tid; i < cntE; i += 256)
        atomicAdd(&hist[dst[beg + i] >> 7], 1);
    __syncthreads();
    for (int b = tid; b < NB; b += 256) {
        int h = hist[b];
        if (h) blockBase[(size_t)blk * NB + b] = atomicAdd(&bucketCnt[b], h);
    }
}

// ---------------------------------------------------------------- exclusive scan of bucketCnt (single wave)
__global__ __launch_bounds__(64) void bucket_scan(const int* __restrict__ bucketCnt,
                                                  int* __restrict__ bucketStart, int NB) {
    int lane = threadIdx.x;
    int CH = (NB + 63) >> 6;
    int base = lane * CH;
    int s = 0;
    for (int i = 0; i < CH; ++i) {
        int idx = base + i;
        if (idx < NB) s += bucketCnt[idx];
    }
    int inc = s;
    for (int off = 1; off < 64; off <<= 1) {
        int y = __shfl_up(inc, off, 64);
        if (lane >= off) inc += y;
    }
    int run = inc - s;          // exclusive over lane segments
    for (int i = 0; i < CH; ++i) {
        int idx = base + i;
        if (idx < NB) { bucketStart[idx] = run; run += bucketCnt[idx]; }
    }
}

// ---------------------------------------------------------------- pass A scatter:
// pos = bucketStart[b] + blockBase[blk][b] + localRank -> contiguous per (block,bucket).
// packed word: src (20 bits) | (dst&127) << 20   (valid for n < 2^20)
__global__ __launch_bounds__(256) void binA_scatter(const int* __restrict__ src,
                                                    const int* __restrict__ dst,
                                                    const int* __restrict__ bucketStart,
                                                    const int* __restrict__ blockBase,
                                                    unsigned int* __restrict__ packed,
                                                    int nE, int NB) {
    __shared__ int cur[MAXNB];
    int tid = threadIdx.x, blk = blockIdx.x;
    int chunk = (nE + NBLK_A - 1) / NBLK_A;
    int beg = blk * chunk;
    int cntE = min(chunk, nE - beg); if (cntE < 0) cntE = 0;

    for (int i = tid; i < NB; i += 256) cur[i] = 0;
    __syncthreads();
    for (int i = tid; i < cntE; i += 256) {
        int s = src[beg + i], d = dst[beg + i];
        int b = d >> 7;
        int r = atomicAdd(&cur[b], 1);
        int pos = bucketStart[b] + blockBase[(size_t)blk * NB + b] + r;
        if ((unsigned)pos < (unsigned)nE)
            packed[pos] = (unsigned)s | ((unsigned)(d & 127) << 20);
    }
}

// ---------------------------------------------------------------- pass B: per-bucket node sort.
// Produces esrc (bucket-local scatter, ~16KB region), cnt[v], row_start[v].
__global__ __launch_bounds__(256) void binB(const unsigned int* __restrict__ packed,
                                            const int* __restrict__ bucketStart,
                                            const int* __restrict__ bucketCnt,
                                            int* __restrict__ esrc, int* __restrict__ cnt,
                                            int* __restrict__ row_start,
                                            int n, int nE) {
    __shared__ int hist[128];
    __shared__ int sdata[256];
    __shared__ int cur[128];
    int b = blockIdx.x, tid = threadIdx.x;
    int nodeFirst = b << 7;
    int bstart = bucketStart[b];
    int bcnt = bucketCnt[b];

    if (tid < 128) hist[tid] = 0;
    __syncthreads();
    for (int i = tid; i < bcnt; i += 256)
        atomicAdd(&hist[(packed[bstart + i] >> 20) & 127], 1);
    __syncthreads();

    int x = (tid < 128) ? hist[tid] : 0;   // Hillis-Steele inclusive scan
    int inc = x;
    sdata[tid] = inc;
    __syncthreads();
    for (int off = 1; off < 256; off <<= 1) {
        int y = (tid >= off) ? sdata[tid - off] : 0;
        __syncthreads();
        inc += y;
        sdata[tid] = inc;
        __syncthreads();
    }
    if (tid < 128) {
        int excl = inc - x;
        int v = nodeFirst + tid;
        if (v < n) { row_start[v] = bstart + excl; cnt[v] = x; }
        cur[tid] = excl;
    }
    __syncthreads();
    for (int i = tid; i < bcnt; i += 256) {
        unsigned w = packed[bstart + i];
        int d127 = (w >> 20) & 127;
        int pos = bstart + atomicAdd(&cur[d127], 1);
        if ((unsigned)pos < (unsigned)nE) esrc[pos] = (int)(w & 0xFFFFFu);
    }
}

// ---------------------------------------------------------------- dis = rsqrt(cnt + 1)
__global__ void dis_kernel(const int* __restrict__ cnt, float* __restrict__ dis, int n) {
    int v = blockIdx.x * blockDim.x + threadIdx.x;
    if (v < n) dis[v] = rsqrtf((float)cnt[v] + 1.0f);
}

// ---------------------------------------------------------------- h1s = (x @ W1) * dis[row]
__global__ __launch_bounds__(64) void xw1s_kernel(const float* __restrict__ x,
                                                  const float* __restrict__ W1,
                                                  const float* __restrict__ dis,
                                                  float* __restrict__ h1s, int n) {
    __shared__ float xs[64][132];   // +4 pad
    int rowbase = blockIdx.x * 64;
    int tid = threadIdx.x;

    const float4* xg = (const float4*)(x + (size_t)rowbase * IN_DIM);
    int rows_here = min(64, n - rowbase);
    int nf4 = rows_here * (IN_DIM / 4);
    for (int i = 0; i < 32; ++i) {
        int f = i * 64 + tid;
        if (f < nf4) {
            int r = f >> 5, kq = f & 31;
            float4 v = xg[f];
            *(float4*)&xs[r][kq * 4] = v;
        }
    }
    __syncthreads();

    int row = rowbase + tid;
    if (row >= n) return;

    float acc[HID];
#pragma unroll
    for (int c = 0; c < HID; ++c) acc[c] = 0.f;

    for (int k = 0; k < IN_DIM; k += 4) {
        float4 xv = *(const float4*)&xs[tid][k];
        const float* xp = (const float*)&xv;
#pragma unroll
        for (int j = 0; j < 4; ++j) {
            float xj = xp[j];
            const float* wrow = &W1[(size_t)(k + j) * HID];
#pragma unroll
            for (int c = 0; c < HID; ++c) acc[c] += xj * wrow[c];
        }
    }
    float dv = dis[row];
    float4* o = (float4*)(h1s + (size_t)row * HID);
    o[0] = make_float4(acc[0] * dv, acc[1] * dv, acc[2] * dv, acc[3] * dv);
    o[1] = make_float4(acc[4] * dv, acc[5] * dv, acc[6] * dv, acc[7] * dv);
    o[2] = make_float4(acc[8] * dv, acc[9] * dv, acc[10] * dv, acc[11] * dv);
    o[3] = make_float4(acc[12] * dv, acc[13] * dv, acc[14] * dv, acc[15] * dv);
}

// ---------------------------------------------------------------- layer-1 gather, fused transform
__global__ void gather1(const int* __restrict__ esrc, const int* __restrict__ row_start,
                        const int* __restrict__ cnt, const float* __restrict__ dis,
                        const float* __restrict__ h1s, const float* __restrict__ b1,
                        const float* __restrict__ W2, float* __restrict__ h2s,
                        int n, int nE) {
    long long t = (long long)blockIdx.x * blockDim.x + threadIdx.x;
    int v = (int)(t >> 2), c4 = (int)(t & 3);
    if (v >= n) return;
    int beg = row_start[v], c = cnt[v];
    if (beg < 0) beg = 0;
    int end = beg + c;
    if (end > nE) end = nE;

    float ax = 0.f, ay = 0.f, az = 0.f, aw = 0.f;
    for (int i = beg; i < end; ++i) {
        int s = esrc[i];
        float4 hv = *(const float4*)&h1s[(size_t)s * HID + c4 * 4];
        ax += hv.x; ay += hv.y; az += hv.z; aw += hv.w;
    }
    float dv = dis[v];
    float4 self = *(const float4*)&h1s[(size_t)v * HID + c4 * 4];
    int cb = c4 * 4;
    float h0 = fmaxf((ax + self.x) * dv + b1[cb + 0], 0.f);
    float h1_ = fmaxf((ay + self.y) * dv + b1[cb + 1], 0.f);
    float h2_ = fmaxf((az + self.z) * dv + b1[cb + 2], 0.f);
    float h3 = fmaxf((aw + self.w) * dv + b1[cb + 3], 0.f);

    float o0 = h0 * W2[(cb + 0) * 2] + h1_ * W2[(cb + 1) * 2]
             + h2_ * W2[(cb + 2) * 2] + h3 * W2[(cb + 3) * 2];
    float o1 = h0 * W2[(cb + 0) * 2 + 1] + h1_ * W2[(cb + 1) * 2 + 1]
             + h2_ * W2[(cb + 2) * 2 + 1] + h3 * W2[(cb + 3) * 2 + 1];
    o0 += __shfl_xor(o0, 1, 64); o0 += __shfl_xor(o0, 2, 64);
    o1 += __shfl_xor(o1, 1, 64); o1 += __shfl_xor(o1, 2, 64);
    if (c4 == 0)
        *(float2*)&h2s[(size_t)v * 2] = make_float2(o0 * dv, o1 * dv);  // pre-scaled
}

// ---------------------------------------------------------------- layer-2 gather + log_softmax
__global__ void gather2(const int* __restrict__ esrc, const int* __restrict__ row_start,
                        const int* __restrict__ cnt, const float* __restrict__ dis,
                        const float* __restrict__ h2s, const float* __restrict__ b2,
                        float* __restrict__ out, int n, int nE) {
    int v = blockIdx.x * blockDim.x + threadIdx.x;
    if (v >= n) return;
    int beg = row_start[v], c = cnt[v];
    if (beg < 0) beg = 0;
    int end = beg + c;
    if (end > nE) end = nE;

    float a0 = 0.f, a1 = 0.f;
    for (int i = beg; i < end; ++i) {
        int s = esrc[i];
        float2 hv = *(const float2*)&h2s[(size_t)s * 2];
        a0 += hv.x; a1 += hv.y;
    }
    float dv = dis[v];
    float2 self = *(const float2*)&h2s[(size_t)v * 2];
    float v0 = (a0 + self.x) * dv + b2[0];
    float v1 = (a1 + self.y) * dv + b2[1];
    float m = fmaxf(v0, v1);
    float lse = m + logf(expf(v0 - m) + expf(v1 - m));
    *(float2*)&out[(size_t)v * 2] = make_float2(v0 - lse, v1 - lse);
}

// ---------------------------------------------------------------- launch
extern "C" void kernel_launch(void* const* d_in, const int* in_sizes, int n_in,
                              void* d_out, int out_size, void* d_ws, size_t ws_size,
                              hipStream_t stream) {
    const float* x  = (const float*)d_in[0];
    const int*   ei = (const int*)d_in[1];   // int32 per harness contract
    const float* W1 = (const float*)d_in[2];
    const float* b1 = (const float*)d_in[3];
    const float* W2 = (const float*)d_in[4];
    const float* b2 = (const float*)d_in[5];
    float* out = (float*)d_out;

    int n  = in_sizes[0] / IN_DIM;   // 200000
    int nE = in_sizes[1] / 2;        // 6400000
    const int* src = ei;
    const int* dst = ei + nE;
    int NB = (n + 127) >> 7;         // 1563 super-buckets

    char* ws = (char*)d_ws;
    size_t off = 0;
    auto take = [&](size_t bytes) {
        char* p = ws + off;
        off += (bytes + 255) & ~(size_t)255;
        return p;
    };
    int*      bucketCnt   = (int*)take((size_t)NB * 4);
    int*      bucketStart = (int*)take((size_t)NB * 4);
    int*      blockBase   = (int*)take((size_t)NBLK_A * NB * 4);   // 1.6 MB
    unsigned* packed      = (unsigned*)take((size_t)nE * 4);        // 25.6 MB
    int*      esrc        = (int*)take((size_t)nE * 4);             // 25.6 MB
    int*      cnt         = (int*)take((size_t)n * 4);
    int*      rowst       = (int*)take((size_t)n * 4);
    float*    dis         = (float*)take((size_t)n * 4);
    float*    h1s         = (float*)take((size_t)n * HID * 4);
    float*    h2s         = (float*)take((size_t)n * 2 * 4);
    (void)ws_size;   // ~70 MB total; round-6 run proved ws_size >= 73 MB

    int B = 256;
    int gN  = (n + B - 1) / B;
    int gN4 = (int)(((long long)n * 4 + B - 1) / B);

    zero_buckets<<<(NB + B - 1) / B, B, 0, stream>>>(bucketCnt, NB);
    binA_count<<<NBLK_A, B, 0, stream>>>(dst, bucketCnt, blockBase, nE, NB);
    bucket_scan<<<1, 64, 0, stream>>>(bucketCnt, bucketStart, NB);
    binA_scatter<<<NBLK_A, B, 0, stream>>>(src, dst, bucketStart, blockBase, packed, nE, NB);
    binB<<<NB, B, 0, stream>>>(packed, bucketStart, bucketCnt, esrc, cnt, rowst, n, nE);
    dis_kernel<<<gN, B, 0, stream>>>(cnt, dis, n);
    xw1s_kernel<<<(n + 63) / 64, 64, 0, stream>>>(x, W1, dis, h1s, n);
    gather1<<<gN4, B, 0, stream>>>(esrc, rowst, cnt, dis, h1s, b1, W2, h2s, n, nE);
    gather2<<<gN, B, 0, stream>>>(esrc, rowst, cnt, dis, h2s, b2, out, n, nE);
}

// Round 11
// 689.002 us; speedup vs baseline: 5.2034x; 1.0737x over previous
//
#include <hip/hip_runtime.h>
#include <cstdint>
#include <cstddef>

#define IN_DIM 128
#define HID 16
#define NBLK_A 1024       // binning blocks (pass A)
#define BSHIFT 10         // 1024 nodes per super-bucket
#define MAXNB 256         // max buckets (n <= 256*1024)

// ---------------------------------------------------------------- zero bucket counters
__global__ void zero_buckets(int* __restrict__ bucketCnt, int NB) {
    int i = blockIdx.x * blockDim.x + threadIdx.x;
    if (i < NB) bucketCnt[i] = 0;
}

// ---------------------------------------------------------------- pass A count
__global__ __launch_bounds__(256) void binA_count(const int* __restrict__ dst,
                                                  int* __restrict__ bucketCnt,
                                                  int* __restrict__ blockBase,
                                                  int nE, int NB) {
    __shared__ int hist[MAXNB];
    int tid = threadIdx.x, blk = blockIdx.x;
    int chunk = (nE + NBLK_A - 1) / NBLK_A;
    int beg = blk * chunk;
    int cntE = min(chunk, nE - beg); if (cntE < 0) cntE = 0;

    for (int i = tid; i < NB; i += 256) hist[i] = 0;
    __syncthreads();
    for (int i = tid; i < cntE; i += 256)
        atomicAdd(&hist[dst[beg + i] >> BSHIFT], 1);
    __syncthreads();
    for (int b = tid; b < NB; b += 256) {
        int h = hist[b];
        if (h) blockBase[(size_t)blk * NB + b] = atomicAdd(&bucketCnt[b], h);
    }
}

// ---------------------------------------------------------------- exclusive scan of bucketCnt (single wave)
__global__ __launch_bounds__(64) void bucket_scan(const int* __restrict__ bucketCnt,
                                                  int* __restrict__ bucketStart, int NB) {
    int lane = threadIdx.x;
    int CH = (NB + 63) >> 6;
    int base = lane * CH;
    int s = 0;
    for (int i = 0; i < CH; ++i) {
        int idx = base + i;
        if (idx < NB) s += bucketCnt[idx];
    }
    int inc = s;
    for (int off = 1; off < 64; off <<= 1) {
        int y = __shfl_up(inc, off, 64);
        if (lane >= off) inc += y;
    }
    int run = inc - s;
    for (int i = 0; i < CH; ++i) {
        int idx = base + i;
        if (idx < NB) { bucketStart[idx] = run; run += bucketCnt[idx]; }
    }
}

// ---------------------------------------------------------------- pass A scatter
// packed word: src (18 bits used of 20) | (dst & 1023) << 20
__global__ __launch_bounds__(256) void binA_scatter(const int* __restrict__ src,
                                                    const int* __restrict__ dst,
                                                    const int* __restrict__ bucketStart,
                                                    const int* __restrict__ blockBase,
                                                    unsigned int* __restrict__ packed,
                                                    int nE, int NB) {
    __shared__ int cur[MAXNB];
    int tid = threadIdx.x, blk = blockIdx.x;
    int chunk = (nE + NBLK_A - 1) / NBLK_A;
    int beg = blk * chunk;
    int cntE = min(chunk, nE - beg); if (cntE < 0) cntE = 0;

    for (int i = tid; i < NB; i += 256) cur[i] = 0;
    __syncthreads();
    for (int i = tid; i < cntE; i += 256) {
        int s = src[beg + i], d = dst[beg + i];
        int b = d >> BSHIFT;
        int r = atomicAdd(&cur[b], 1);
        int pos = bucketStart[b] + blockBase[(size_t)blk * NB + b] + r;
        if ((unsigned)pos < (unsigned)nE)
            packed[pos] = (unsigned)s | ((unsigned)(d & 1023) << 20);
    }
}

// ---------------------------------------------------------------- pass B: per-bucket node sort
// Produces esrc (bucket-local scatter, ~132KB region), cnt, row_start, dis.
__global__ __launch_bounds__(256) void binB(const unsigned int* __restrict__ packed,
                                            const int* __restrict__ bucketStart,
                                            const int* __restrict__ bucketCnt,
                                            int* __restrict__ esrc, int* __restrict__ cnt,
                                            int* __restrict__ row_start, float* __restrict__ dis,
                                            int n, int nE) {
    __shared__ int hist[1024];
    __shared__ int cur[1024];
    __shared__ int sdata[256];
    int b = blockIdx.x, tid = threadIdx.x;
    int nodeFirst = b << BSHIFT;
    int bstart = bucketStart[b];
    int bcnt = bucketCnt[b];

    for (int i = tid; i < 1024; i += 256) hist[i] = 0;
    __syncthreads();
    for (int i = tid; i < bcnt; i += 256)
        atomicAdd(&hist[(packed[bstart + i] >> 20) & 1023], 1);
    __syncthreads();

    // 1024-wide exclusive scan: per-thread 4 elements + block scan of sums
    int base4 = tid * 4;
    int h0 = hist[base4], h1 = hist[base4 + 1], h2 = hist[base4 + 2], h3 = hist[base4 + 3];
    int tsum = h0 + h1 + h2 + h3;
    sdata[tid] = tsum;
    __syncthreads();
    int inc = tsum;
    for (int off = 1; off < 256; off <<= 1) {
        int y = (tid >= off) ? sdata[tid - off] : 0;
        __syncthreads();
        inc += y;
        sdata[tid] = inc;
        __syncthreads();
    }
    int excl = inc - tsum;
    int e0 = excl, e1 = excl + h0, e2 = e1 + h1, e3 = e2 + h2;
    cur[base4] = e0; cur[base4 + 1] = e1; cur[base4 + 2] = e2; cur[base4 + 3] = e3;
    int v0n = nodeFirst + base4;
#pragma unroll
    for (int j = 0; j < 4; ++j) {
        int v = v0n + j;
        if (v < n) {
            int hj = (j == 0) ? h0 : (j == 1) ? h1 : (j == 2) ? h2 : h3;
            int ej = (j == 0) ? e0 : (j == 1) ? e1 : (j == 2) ? e2 : e3;
            row_start[v] = bstart + ej;
            cnt[v] = hj;
            dis[v] = rsqrtf((float)hj + 1.0f);
        }
    }
    __syncthreads();
    for (int i = tid; i < bcnt; i += 256) {
        unsigned w = packed[bstart + i];
        int d10 = (w >> 20) & 1023;
        int pos = bstart + atomicAdd(&cur[d10], 1);
        if ((unsigned)pos < (unsigned)nE) esrc[pos] = (int)(w & 0xFFFFFu);
    }
}

// ---------------------------------------------------------------- h1s = (x @ W1) * dis[row]
__global__ __launch_bounds__(64) void xw1s_kernel(const float* __restrict__ x,
                                                  const float* __restrict__ W1,
                                                  const float* __restrict__ dis,
                                                  float* __restrict__ h1s, int n) {
    __shared__ float xs[64][132];   // +4 pad
    int rowbase = blockIdx.x * 64;
    int tid = threadIdx.x;

    const float4* xg = (const float4*)(x + (size_t)rowbase * IN_DIM);
    int rows_here = min(64, n - rowbase);
    int nf4 = rows_here * (IN_DIM / 4);
    for (int i = 0; i < 32; ++i) {
        int f = i * 64 + tid;
        if (f < nf4) {
            int r = f >> 5, kq = f & 31;
            float4 v = xg[f];
            *(float4*)&xs[r][kq * 4] = v;
        }
    }
    __syncthreads();

    int row = rowbase + tid;
    if (row >= n) return;

    float acc[HID];
#pragma unroll
    for (int c = 0; c < HID; ++c) acc[c] = 0.f;

    for (int k = 0; k < IN_DIM; k += 4) {
        float4 xv = *(const float4*)&xs[tid][k];
        const float* xp = (const float*)&xv;
#pragma unroll
        for (int j = 0; j < 4; ++j) {
            float xj = xp[j];
            const float* wrow = &W1[(size_t)(k + j) * HID];
#pragma unroll
            for (int c = 0; c < HID; ++c) acc[c] += xj * wrow[c];
        }
    }
    float dv = dis[row];
    float4* o = (float4*)(h1s + (size_t)row * HID);
    o[0] = make_float4(acc[0] * dv, acc[1] * dv, acc[2] * dv, acc[3] * dv);
    o[1] = make_float4(acc[4] * dv, acc[5] * dv, acc[6] * dv, acc[7] * dv);
    o[2] = make_float4(acc[8] * dv, acc[9] * dv, acc[10] * dv, acc[11] * dv);
    o[3] = make_float4(acc[12] * dv, acc[13] * dv, acc[14] * dv, acc[15] * dv);
}

// ---------------------------------------------------------------- layer-1 gather, fused transform
__global__ void gather1(const int* __restrict__ esrc, const int* __restrict__ row_start,
                        const int* __restrict__ cnt, const float* __restrict__ dis,
                        const float* __restrict__ h1s, const float* __restrict__ b1,
                        const float* __restrict__ W2, float* __restrict__ h2s,
                        int n, int nE) {
    long long t = (long long)blockIdx.x * blockDim.x + threadIdx.x;
    int v = (int)(t >> 2), c4 = (int)(t & 3);
    if (v >= n) return;
    int beg = row_start[v], c = cnt[v];
    if (beg < 0) beg = 0;
    int end = beg + c;
    if (end > nE) end = nE;

    float ax = 0.f, ay = 0.f, az = 0.f, aw = 0.f;
    for (int i = beg; i < end; ++i) {
        int s = esrc[i];
        float4 hv = *(const float4*)&h1s[(size_t)s * HID + c4 * 4];
        ax += hv.x; ay += hv.y; az += hv.z; aw += hv.w;
    }
    float dv = dis[v];
    float4 self = *(const float4*)&h1s[(size_t)v * HID + c4 * 4];
    int cb = c4 * 4;
    float h0 = fmaxf((ax + self.x) * dv + b1[cb + 0], 0.f);
    float h1_ = fmaxf((ay + self.y) * dv + b1[cb + 1], 0.f);
    float h2_ = fmaxf((az + self.z) * dv + b1[cb + 2], 0.f);
    float h3 = fmaxf((aw + self.w) * dv + b1[cb + 3], 0.f);

    float o0 = h0 * W2[(cb + 0) * 2] + h1_ * W2[(cb + 1) * 2]
             + h2_ * W2[(cb + 2) * 2] + h3 * W2[(cb + 3) * 2];
    float o1 = h0 * W2[(cb + 0) * 2 + 1] + h1_ * W2[(cb + 1) * 2 + 1]
             + h2_ * W2[(cb + 2) * 2 + 1] + h3 * W2[(cb + 3) * 2 + 1];
    o0 += __shfl_xor(o0, 1, 64); o0 += __shfl_xor(o0, 2, 64);
    o1 += __shfl_xor(o1, 1, 64); o1 += __shfl_xor(o1, 2, 64);
    if (c4 == 0)
        *(float2*)&h2s[(size_t)v * 2] = make_float2(o0 * dv, o1 * dv);  // pre-scaled
}

// ---------------------------------------------------------------- layer-2 gather + log_softmax
__global__ void gather2(const int* __restrict__ esrc, const int* __restrict__ row_start,
                        const int* __restrict__ cnt, const float* __restrict__ dis,
                        const float* __restrict__ h2s, const float* __restrict__ b2,
                        float* __restrict__ out, int n, int nE) {
    int v = blockIdx.x * blockDim.x + threadIdx.x;
    if (v >= n) return;
    int beg = row_start[v], c = cnt[v];
    if (beg < 0) beg = 0;
    int end = beg + c;
    if (end > nE) end = nE;

    float a0 = 0.f, a1 = 0.f;
    for (int i = beg; i < end; ++i) {
        int s = esrc[i];
        float2 hv = *(const float2*)&h2s[(size_t)s * 2];
        a0 += hv.x; a1 += hv.y;
    }
    float dv = dis[v];
    float2 self = *(const float2*)&h2s[(size_t)v * 2];
    float v0 = (a0 + self.x) * dv + b2[0];
    float v1 = (a1 + self.y) * dv + b2[1];
    float m = fmaxf(v0, v1);
    float lse = m + logf(expf(v0 - m) + expf(v1 - m));
    *(float2*)&out[(size_t)v * 2] = make_float2(v0 - lse, v1 - lse);
}

// ---------------------------------------------------------------- launch
extern "C" void kernel_launch(void* const* d_in, const int* in_sizes, int n_in,
                              void* d_out, int out_size, void* d_ws, size_t ws_size,
                              hipStream_t stream) {
    const float* x  = (const float*)d_in[0];
    const int*   ei = (const int*)d_in[1];   // int32 per harness contract
    const float* W1 = (const float*)d_in[2];
    const float* b1 = (const float*)d_in[3];
    const float* W2 = (const float*)d_in[4];
    const float* b2 = (const float*)d_in[5];
    float* out = (float*)d_out;

    int n  = in_sizes[0] / IN_DIM;   // 200000
    int nE = in_sizes[1] / 2;        // 6400000
    const int* src = ei;
    const int* dst = ei + nE;
    int NB = (n + (1 << BSHIFT) - 1) >> BSHIFT;   // 196 super-buckets

    char* ws = (char*)d_ws;
    size_t off = 0;
    auto take = [&](size_t bytes) {
        char* p = ws + off;
        off += (bytes + 255) & ~(size_t)255;
        return p;
    };
    int*      bucketCnt   = (int*)take((size_t)NB * 4);
    int*      bucketStart = (int*)take((size_t)NB * 4);
    int*      blockBase   = (int*)take((size_t)NBLK_A * NB * 4);   // 0.8 MB
    unsigned* packed      = (unsigned*)take((size_t)nE * 4);        // 25.6 MB
    int*      esrc        = (int*)take((size_t)nE * 4);             // 25.6 MB
    int*      cnt         = (int*)take((size_t)n * 4);
    int*      rowst       = (int*)take((size_t)n * 4);
    float*    dis         = (float*)take((size_t)n * 4);
    float*    h1s         = (float*)take((size_t)n * HID * 4);
    float*    h2s         = (float*)take((size_t)n * 2 * 4);
    (void)ws_size;   // ~69 MB total (ws >= 73 MB proven in round 6)

    int B = 256;
    int gN  = (n + B - 1) / B;
    int gN4 = (int)(((long long)n * 4 + B - 1) / B);

    zero_buckets<<<(NB + B - 1) / B, B, 0, stream>>>(bucketCnt, NB);
    binA_count<<<NBLK_A, B, 0, stream>>>(dst, bucketCnt, blockBase, nE, NB);
    bucket_scan<<<1, 64, 0, stream>>>(bucketCnt, bucketStart, NB);
    binA_scatter<<<NBLK_A, B, 0, stream>>>(src, dst, bucketStart, blockBase, packed, nE, NB);
    binB<<<NB, B, 0, stream>>>(packed, bucketStart, bucketCnt, esrc, cnt, rowst, dis, n, nE);
    xw1s_kernel<<<(n + 63) / 64, 64, 0, stream>>>(x, W1, dis, h1s, n);
    gather1<<<gN4, B, 0, stream>>>(esrc, rowst, cnt, dis, h1s, b1, W2, h2s, n, nE);
    gather2<<<gN, B, 0, stream>>>(esrc, rowst, cnt, dis, h2s, b2, out, n, nE);
}

// Round 12
// 618.752 us; speedup vs baseline: 5.7942x; 1.1135x over previous
//
#include <hip/hip_runtime.h>
#include <hip/hip_fp16.h>
#include <cstdint>
#include <cstddef>

#define IN_DIM 128
#define HID 16
#define NBLK_A 1024       // binning blocks (pass A)
#define BSHIFT 10         // 1024 nodes per super-bucket
#define MAXNB 256         // max buckets (n <= 256*1024)

// fp16 pack/unpack helpers (register-level, no memory round-trip)
static __device__ inline unsigned pk2(float a, float b) {
    union { __half2 h; unsigned u; } c;
    c.h = __floats2half2_rn(a, b);
    return c.u;
}
static __device__ inline float2 up2(unsigned w) {
    union { unsigned u; __half2 h; } c;
    c.u = w;
    return __half22float2(c.h);
}

// ---------------------------------------------------------------- zero bucket counters
__global__ void zero_buckets(int* __restrict__ bucketCnt, int NB) {
    int i = blockIdx.x * blockDim.x + threadIdx.x;
    if (i < NB) bucketCnt[i] = 0;
}

// ---------------------------------------------------------------- pass A count
__global__ __launch_bounds__(256) void binA_count(const int* __restrict__ dst,
                                                  int* __restrict__ bucketCnt,
                                                  int* __restrict__ blockBase,
                                                  int nE, int NB) {
    __shared__ int hist[MAXNB];
    int tid = threadIdx.x, blk = blockIdx.x;
    int chunk = (nE + NBLK_A - 1) / NBLK_A;
    int beg = blk * chunk;
    int cntE = min(chunk, nE - beg); if (cntE < 0) cntE = 0;

    for (int i = tid; i < NB; i += 256) hist[i] = 0;
    __syncthreads();
    for (int i = tid; i < cntE; i += 256)
        atomicAdd(&hist[dst[beg + i] >> BSHIFT], 1);
    __syncthreads();
    for (int b = tid; b < NB; b += 256) {
        int h = hist[b];
        if (h) blockBase[(size_t)blk * NB + b] = atomicAdd(&bucketCnt[b], h);
    }
}

// ---------------------------------------------------------------- exclusive scan of bucketCnt (single wave)
__global__ __launch_bounds__(64) void bucket_scan(const int* __restrict__ bucketCnt,
                                                  int* __restrict__ bucketStart, int NB) {
    int lane = threadIdx.x;
    int CH = (NB + 63) >> 6;
    int base = lane * CH;
    int s = 0;
    for (int i = 0; i < CH; ++i) {
        int idx = base + i;
        if (idx < NB) s += bucketCnt[idx];
    }
    int inc = s;
    for (int off = 1; off < 64; off <<= 1) {
        int y = __shfl_up(inc, off, 64);
        if (lane >= off) inc += y;
    }
    int run = inc - s;
    for (int i = 0; i < CH; ++i) {
        int idx = base + i;
        if (idx < NB) { bucketStart[idx] = run; run += bucketCnt[idx]; }
    }
}

// ---------------------------------------------------------------- pass A scatter
// packed word: src (18 bits used of 20) | (dst & 1023) << 20
__global__ __launch_bounds__(256) void binA_scatter(const int* __restrict__ src,
                                                    const int* __restrict__ dst,
                                                    const int* __restrict__ bucketStart,
                                                    const int* __restrict__ blockBase,
                                                    unsigned int* __restrict__ packed,
                                                    int nE, int NB) {
    __shared__ int cur[MAXNB];
    int tid = threadIdx.x, blk = blockIdx.x;
    int chunk = (nE + NBLK_A - 1) / NBLK_A;
    int beg = blk * chunk;
    int cntE = min(chunk, nE - beg); if (cntE < 0) cntE = 0;

    for (int i = tid; i < NB; i += 256) cur[i] = 0;
    __syncthreads();
    for (int i = tid; i < cntE; i += 256) {
        int s = src[beg + i], d = dst[beg + i];
        int b = d >> BSHIFT;
        int r = atomicAdd(&cur[b], 1);
        int pos = bucketStart[b] + blockBase[(size_t)blk * NB + b] + r;
        if ((unsigned)pos < (unsigned)nE)
            packed[pos] = (unsigned)s | ((unsigned)(d & 1023) << 20);
    }
}

// ---------------------------------------------------------------- pass B: per-bucket node sort, 1024 threads
// One node per thread for hist/scan; produces esrc, cnt, row_start, dis.
__global__ __launch_bounds__(1024) void binB(const unsigned int* __restrict__ packed,
                                             const int* __restrict__ bucketStart,
                                             const int* __restrict__ bucketCnt,
                                             int* __restrict__ esrc, int* __restrict__ cnt,
                                             int* __restrict__ row_start, float* __restrict__ dis,
                                             int n, int nE) {
    __shared__ int hist[1024];
    __shared__ int cur[1024];
    __shared__ int sdata[1024];
    int b = blockIdx.x, tid = threadIdx.x;
    int bstart = bucketStart[b];
    int bcnt = bucketCnt[b];

    hist[tid] = 0;
    __syncthreads();
    for (int i = tid; i < bcnt; i += 1024)
        atomicAdd(&hist[(packed[bstart + i] >> 20) & 1023], 1);
    __syncthreads();

    int h = hist[tid];
    int inc = h;
    sdata[tid] = inc;
    __syncthreads();
    for (int off = 1; off < 1024; off <<= 1) {
        int y = (tid >= off) ? sdata[tid - off] : 0;
        __syncthreads();
        inc += y;
        sdata[tid] = inc;
        __syncthreads();
    }
    int excl = inc - h;
    cur[tid] = excl;
    int v = (b << BSHIFT) + tid;
    if (v < n) {
        row_start[v] = bstart + excl;
        cnt[v] = h;
        dis[v] = rsqrtf((float)h + 1.0f);
    }
    __syncthreads();
    for (int i = tid; i < bcnt; i += 1024) {
        unsigned w = packed[bstart + i];
        int pos = bstart + atomicAdd(&cur[(w >> 20) & 1023], 1);
        if ((unsigned)pos < (unsigned)nE) esrc[pos] = (int)(w & 0xFFFFFu);
    }
}

// ---------------------------------------------------------------- h1s = fp16( (x @ W1) * dis[row] )
__global__ __launch_bounds__(64) void xw1s_kernel(const float* __restrict__ x,
                                                  const float* __restrict__ W1,
                                                  const float* __restrict__ dis,
                                                  __half* __restrict__ h1s, int n) {
    __shared__ float xs[64][132];   // +4 pad
    int rowbase = blockIdx.x * 64;
    int tid = threadIdx.x;

    const float4* xg = (const float4*)(x + (size_t)rowbase * IN_DIM);
    int rows_here = min(64, n - rowbase);
    int nf4 = rows_here * (IN_DIM / 4);
    for (int i = 0; i < 32; ++i) {
        int f = i * 64 + tid;
        if (f < nf4) {
            int r = f >> 5, kq = f & 31;
            float4 v = xg[f];
            *(float4*)&xs[r][kq * 4] = v;
        }
    }
    __syncthreads();

    int row = rowbase + tid;
    if (row >= n) return;

    float acc[HID];
#pragma unroll
    for (int c = 0; c < HID; ++c) acc[c] = 0.f;

    for (int k = 0; k < IN_DIM; k += 4) {
        float4 xv = *(const float4*)&xs[tid][k];
        const float* xp = (const float*)&xv;
#pragma unroll
        for (int j = 0; j < 4; ++j) {
            float xj = xp[j];
            const float* wrow = &W1[(size_t)(k + j) * HID];
#pragma unroll
            for (int c = 0; c < HID; ++c) acc[c] += xj * wrow[c];
        }
    }
    float dv = dis[row];
    uint4 w0 = make_uint4(pk2(acc[0] * dv, acc[1] * dv),  pk2(acc[2] * dv, acc[3] * dv),
                          pk2(acc[4] * dv, acc[5] * dv),  pk2(acc[6] * dv, acc[7] * dv));
    uint4 w1 = make_uint4(pk2(acc[8] * dv, acc[9] * dv),  pk2(acc[10] * dv, acc[11] * dv),
                          pk2(acc[12] * dv, acc[13] * dv), pk2(acc[14] * dv, acc[15] * dv));
    *(uint4*)&h1s[(size_t)row * HID]     = w0;   // 32B-aligned row
    *(uint4*)&h1s[(size_t)row * HID + 8] = w1;
}

// ---------------------------------------------------------------- layer-1 gather (fp16 reads), fused transform
__global__ void gather1(const int* __restrict__ esrc, const int* __restrict__ row_start,
                        const int* __restrict__ cnt, const float* __restrict__ dis,
                        const __half* __restrict__ h1s, const float* __restrict__ b1,
                        const float* __restrict__ W2, unsigned* __restrict__ h2s,
                        int n, int nE) {
    long long t = (long long)blockIdx.x * blockDim.x + threadIdx.x;
    int v = (int)(t >> 2), c4 = (int)(t & 3);
    if (v >= n) return;
    int beg = row_start[v], c = cnt[v];
    if (beg < 0) beg = 0;
    int end = beg + c;
    if (end > nE) end = nE;

    float ax = 0.f, ay = 0.f, az = 0.f, aw = 0.f;
    for (int i = beg; i < end; ++i) {
        int s = esrc[i];
        uint2 w = *(const uint2*)(h1s + (size_t)s * HID + c4 * 4);   // 8B fp16x4
        float2 f01 = up2(w.x), f23 = up2(w.y);
        ax += f01.x; ay += f01.y; az += f23.x; aw += f23.y;
    }
    float dv = dis[v];
    uint2 ws = *(const uint2*)(h1s + (size_t)v * HID + c4 * 4);
    float2 s01 = up2(ws.x), s23 = up2(ws.y);
    int cb = c4 * 4;
    float h0  = fmaxf((ax + s01.x) * dv + b1[cb + 0], 0.f);
    float h1_ = fmaxf((ay + s01.y) * dv + b1[cb + 1], 0.f);
    float h2_ = fmaxf((az + s23.x) * dv + b1[cb + 2], 0.f);
    float h3  = fmaxf((aw + s23.y) * dv + b1[cb + 3], 0.f);

    float o0 = h0 * W2[(cb + 0) * 2] + h1_ * W2[(cb + 1) * 2]
             + h2_ * W2[(cb + 2) * 2] + h3 * W2[(cb + 3) * 2];
    float o1 = h0 * W2[(cb + 0) * 2 + 1] + h1_ * W2[(cb + 1) * 2 + 1]
             + h2_ * W2[(cb + 2) * 2 + 1] + h3 * W2[(cb + 3) * 2 + 1];
    o0 += __shfl_xor(o0, 1, 64); o0 += __shfl_xor(o0, 2, 64);
    o1 += __shfl_xor(o1, 1, 64); o1 += __shfl_xor(o1, 2, 64);
    if (c4 == 0)
        h2s[v] = pk2(o0 * dv, o1 * dv);   // pre-scaled, fp16x2
}

// ---------------------------------------------------------------- layer-2 gather + log_softmax
__global__ void gather2(const int* __restrict__ esrc, const int* __restrict__ row_start,
                        const int* __restrict__ cnt, const float* __restrict__ dis,
                        const unsigned* __restrict__ h2s, const float* __restrict__ b2,
                        float* __restrict__ out, int n, int nE) {
    int v = blockIdx.x * blockDim.x + threadIdx.x;
    if (v >= n) return;
    int beg = row_start[v], c = cnt[v];
    if (beg < 0) beg = 0;
    int end = beg + c;
    if (end > nE) end = nE;

    float a0 = 0.f, a1 = 0.f;
    for (int i = beg; i < end; ++i) {
        float2 f = up2(h2s[esrc[i]]);
        a0 += f.x; a1 += f.y;
    }
    float dv = dis[v];
    float2 self = up2(h2s[v]);
    float v0 = (a0 + self.x) * dv + b2[0];
    float v1 = (a1 + self.y) * dv + b2[1];
    float m = fmaxf(v0, v1);
    float lse = m + logf(expf(v0 - m) + expf(v1 - m));
    *(float2*)&out[(size_t)v * 2] = make_float2(v0 - lse, v1 - lse);
}

// ---------------------------------------------------------------- launch
extern "C" void kernel_launch(void* const* d_in, const int* in_sizes, int n_in,
                              void* d_out, int out_size, void* d_ws, size_t ws_size,
                              hipStream_t stream) {
    const float* x  = (const float*)d_in[0];
    const int*   ei = (const int*)d_in[1];   // int32 per harness contract
    const float* W1 = (const float*)d_in[2];
    const float* b1 = (const float*)d_in[3];
    const float* W2 = (const float*)d_in[4];
    const float* b2 = (const float*)d_in[5];
    float* out = (float*)d_out;

    int n  = in_sizes[0] / IN_DIM;   // 200000
    int nE = in_sizes[1] / 2;        // 6400000
    const int* src = ei;
    const int* dst = ei + nE;
    int NB = (n + (1 << BSHIFT) - 1) >> BSHIFT;   // 196 super-buckets

    char* ws = (char*)d_ws;
    size_t off = 0;
    auto take = [&](size_t bytes) {
        char* p = ws + off;
        off += (bytes + 255) & ~(size_t)255;
        return p;
    };
    int*      bucketCnt   = (int*)take((size_t)NB * 4);
    int*      bucketStart = (int*)take((size_t)NB * 4);
    int*      blockBase   = (int*)take((size_t)NBLK_A * NB * 4);   // 0.8 MB
    unsigned* packed      = (unsigned*)take((size_t)nE * 4);        // 25.6 MB
    int*      esrc        = (int*)take((size_t)nE * 4);             // 25.6 MB
    int*      cnt         = (int*)take((size_t)n * 4);
    int*      rowst       = (int*)take((size_t)n * 4);
    float*    dis         = (float*)take((size_t)n * 4);
    __half*   h1s         = (__half*)take((size_t)n * HID * 2);     // 6.4 MB fp16
    unsigned* h2s         = (unsigned*)take((size_t)n * 4);         // fp16x2
    (void)ws_size;   // ~62 MB total (ws >= 73 MB proven in round 6)

    int B = 256;
    int gN  = (n + B - 1) / B;
    int gN4 = (int)(((long long)n * 4 + B - 1) / B);

    zero_buckets<<<(NB + B - 1) / B, B, 0, stream>>>(bucketCnt, NB);
    binA_count<<<NBLK_A, B, 0, stream>>>(dst, bucketCnt, blockBase, nE, NB);
    bucket_scan<<<1, 64, 0, stream>>>(bucketCnt, bucketStart, NB);
    binA_scatter<<<NBLK_A, B, 0, stream>>>(src, dst, bucketStart, blockBase, packed, nE, NB);
    binB<<<NB, 1024, 0, stream>>>(packed, bucketStart, bucketCnt, esrc, cnt, rowst, dis, n, nE);
    xw1s_kernel<<<(n + 63) / 64, 64, 0, stream>>>(x, W1, dis, h1s, n);
    gather1<<<gN4, B, 0, stream>>>(esrc, rowst, cnt, dis, h1s, b1, W2, h2s, n, nE);
    gather2<<<gN, B, 0, stream>>>(esrc, rowst, cnt, dis, h2s, b2, out, n, nE);
}

// Round 13
// 555.640 us; speedup vs baseline: 6.4524x; 1.1136x over previous
//
#include <hip/hip_runtime.h>
#include <hip/hip_fp16.h>
#include <cstdint>
#include <cstddef>

#define IN_DIM 128
#define HID 16
#define NBLK_A 1024       // binning blocks (pass A)
#define BSHIFT 10         // 1024 nodes per super-bucket
#define MAXNB 256         // max buckets (n <= 256*1024)

// fp16 pack/unpack helpers (register-level, no memory round-trip)
static __device__ inline unsigned pk2(float a, float b) {
    union { __half2 h; unsigned u; } c;
    c.h = __floats2half2_rn(a, b);
    return c.u;
}
static __device__ inline float2 up2(unsigned w) {
    union { unsigned u; __half2 h; } c;
    c.u = w;
    return __half22float2(c.h);
}

// ---------------------------------------------------------------- zero bucket counters
__global__ void zero_buckets(int* __restrict__ bucketCnt, int NB) {
    int i = blockIdx.x * blockDim.x + threadIdx.x;
    if (i < NB) bucketCnt[i] = 0;
}

// ---------------------------------------------------------------- pass A count
__global__ __launch_bounds__(256) void binA_count(const int* __restrict__ dst,
                                                  int* __restrict__ bucketCnt,
                                                  int* __restrict__ blockBase,
                                                  int nE, int NB) {
    __shared__ int hist[MAXNB];
    int tid = threadIdx.x, blk = blockIdx.x;
    int chunk = (nE + NBLK_A - 1) / NBLK_A;
    int beg = blk * chunk;
    int cntE = min(chunk, nE - beg); if (cntE < 0) cntE = 0;

    for (int i = tid; i < NB; i += 256) hist[i] = 0;
    __syncthreads();
    for (int i = tid; i < cntE; i += 256)
        atomicAdd(&hist[dst[beg + i] >> BSHIFT], 1);
    __syncthreads();
    for (int b = tid; b < NB; b += 256) {
        int h = hist[b];
        if (h) blockBase[(size_t)blk * NB + b] = atomicAdd(&bucketCnt[b], h);
    }
}

// ---------------------------------------------------------------- exclusive scan of bucketCnt (single wave)
__global__ __launch_bounds__(64) void bucket_scan(const int* __restrict__ bucketCnt,
                                                  int* __restrict__ bucketStart, int NB) {
    int lane = threadIdx.x;
    int CH = (NB + 63) >> 6;
    int base = lane * CH;
    int s = 0;
    for (int i = 0; i < CH; ++i) {
        int idx = base + i;
        if (idx < NB) s += bucketCnt[idx];
    }
    int inc = s;
    for (int off = 1; off < 64; off <<= 1) {
        int y = __shfl_up(inc, off, 64);
        if (lane >= off) inc += y;
    }
    int run = inc - s;
    for (int i = 0; i < CH; ++i) {
        int idx = base + i;
        if (idx < NB) { bucketStart[idx] = run; run += bucketCnt[idx]; }
    }
}

// ---------------------------------------------------------------- pass A scatter
// packed word: src (18 bits used of 20) | (dst & 1023) << 20
__global__ __launch_bounds__(256) void binA_scatter(const int* __restrict__ src,
                                                    const int* __restrict__ dst,
                                                    const int* __restrict__ bucketStart,
                                                    const int* __restrict__ blockBase,
                                                    unsigned int* __restrict__ packed,
                                                    int nE, int NB) {
    __shared__ int cur[MAXNB];
    int tid = threadIdx.x, blk = blockIdx.x;
    int chunk = (nE + NBLK_A - 1) / NBLK_A;
    int beg = blk * chunk;
    int cntE = min(chunk, nE - beg); if (cntE < 0) cntE = 0;

    for (int i = tid; i < NB; i += 256) cur[i] = 0;
    __syncthreads();
    for (int i = tid; i < cntE; i += 256) {
        int s = src[beg + i], d = dst[beg + i];
        int b = d >> BSHIFT;
        int r = atomicAdd(&cur[b], 1);
        int pos = bucketStart[b] + blockBase[(size_t)blk * NB + b] + r;
        if ((unsigned)pos < (unsigned)nE)
            packed[pos] = (unsigned)s | ((unsigned)(d & 1023) << 20);
    }
}

// ---------------------------------------------------------------- pass B: per-bucket node sort, 1024 threads
__global__ __launch_bounds__(1024) void binB(const unsigned int* __restrict__ packed,
                                             const int* __restrict__ bucketStart,
                                             const int* __restrict__ bucketCnt,
                                             int* __restrict__ esrc, int* __restrict__ cnt,
                                             int* __restrict__ row_start, float* __restrict__ dis,
                                             int n, int nE) {
    __shared__ int hist[1024];
    __shared__ int cur[1024];
    __shared__ int sdata[1024];
    int b = blockIdx.x, tid = threadIdx.x;
    int bstart = bucketStart[b];
    int bcnt = bucketCnt[b];

    hist[tid] = 0;
    __syncthreads();
    for (int i = tid; i < bcnt; i += 1024)
        atomicAdd(&hist[(packed[bstart + i] >> 20) & 1023], 1);
    __syncthreads();

    int h = hist[tid];
    int inc = h;
    sdata[tid] = inc;
    __syncthreads();
    for (int off = 1; off < 1024; off <<= 1) {
        int y = (tid >= off) ? sdata[tid - off] : 0;
        __syncthreads();
        inc += y;
        sdata[tid] = inc;
        __syncthreads();
    }
    int excl = inc - h;
    cur[tid] = excl;
    int v = (b << BSHIFT) + tid;
    if (v < n) {
        row_start[v] = bstart + excl;
        cnt[v] = h;
        dis[v] = rsqrtf((float)h + 1.0f);
    }
    __syncthreads();
    for (int i = tid; i < bcnt; i += 1024) {
        unsigned w = packed[bstart + i];
        int pos = bstart + atomicAdd(&cur[(w >> 20) & 1023], 1);
        if ((unsigned)pos < (unsigned)nE) esrc[pos] = (int)(w & 0xFFFFFu);
    }
}

// ---------------------------------------------------------------- h1s = fp16( (x @ W1) * dis[row] )
// LDS-free: one row per thread, direct float4 streaming. Each 64B line is
// consumed across 4 consecutive k-steps from L1 -> compulsory HBM traffic only.
// 256-thread blocks, no LDS -> occupancy VGPR-bound (~8 waves/SIMD vs 1 before).
__global__ __launch_bounds__(256) void xw1s_kernel(const float* __restrict__ x,
                                                   const float* __restrict__ W1,
                                                   const float* __restrict__ dis,
                                                   __half* __restrict__ h1s, int n) {
    int row = blockIdx.x * blockDim.x + threadIdx.x;
    if (row >= n) return;

    const float4* xr = (const float4*)(x + (size_t)row * IN_DIM);
    float acc[HID];
#pragma unroll
    for (int c = 0; c < HID; ++c) acc[c] = 0.f;

#pragma unroll 8
    for (int kq = 0; kq < IN_DIM / 4; ++kq) {
        float4 xv = xr[kq];
        const float* xp = (const float*)&xv;
#pragma unroll
        for (int j = 0; j < 4; ++j) {
            float xj = xp[j];
            const float* wrow = &W1[(size_t)(kq * 4 + j) * HID];  // uniform -> s_load
#pragma unroll
            for (int c = 0; c < HID; ++c) acc[c] += xj * wrow[c];
        }
    }
    float dv = dis[row];
    uint4 w0 = make_uint4(pk2(acc[0] * dv, acc[1] * dv),  pk2(acc[2] * dv, acc[3] * dv),
                          pk2(acc[4] * dv, acc[5] * dv),  pk2(acc[6] * dv, acc[7] * dv));
    uint4 w1 = make_uint4(pk2(acc[8] * dv, acc[9] * dv),  pk2(acc[10] * dv, acc[11] * dv),
                          pk2(acc[12] * dv, acc[13] * dv), pk2(acc[14] * dv, acc[15] * dv));
    *(uint4*)&h1s[(size_t)row * HID]     = w0;   // 32B-aligned row
    *(uint4*)&h1s[(size_t)row * HID + 8] = w1;
}

// ---------------------------------------------------------------- layer-1 gather (fp16 reads), fused transform
__global__ void gather1(const int* __restrict__ esrc, const int* __restrict__ row_start,
                        const int* __restrict__ cnt, const float* __restrict__ dis,
                        const __half* __restrict__ h1s, const float* __restrict__ b1,
                        const float* __restrict__ W2, unsigned* __restrict__ h2s,
                        int n, int nE) {
    long long t = (long long)blockIdx.x * blockDim.x + threadIdx.x;
    int v = (int)(t >> 2), c4 = (int)(t & 3);
    if (v >= n) return;
    int beg = row_start[v], c = cnt[v];
    if (beg < 0) beg = 0;
    int end = beg + c;
    if (end > nE) end = nE;

    float ax = 0.f, ay = 0.f, az = 0.f, aw = 0.f;
    for (int i = beg; i < end; ++i) {
        int s = esrc[i];
        uint2 w = *(const uint2*)(h1s + (size_t)s * HID + c4 * 4);   // 8B fp16x4
        float2 f01 = up2(w.x), f23 = up2(w.y);
        ax += f01.x; ay += f01.y; az += f23.x; aw += f23.y;
    }
    float dv = dis[v];
    uint2 ws = *(const uint2*)(h1s + (size_t)v * HID + c4 * 4);
    float2 s01 = up2(ws.x), s23 = up2(ws.y);
    int cb = c4 * 4;
    float h0  = fmaxf((ax + s01.x) * dv + b1[cb + 0], 0.f);
    float h1_ = fmaxf((ay + s01.y) * dv + b1[cb + 1], 0.f);
    float h2_ = fmaxf((az + s23.x) * dv + b1[cb + 2], 0.f);
    float h3  = fmaxf((aw + s23.y) * dv + b1[cb + 3], 0.f);

    float o0 = h0 * W2[(cb + 0) * 2] + h1_ * W2[(cb + 1) * 2]
             + h2_ * W2[(cb + 2) * 2] + h3 * W2[(cb + 3) * 2];
    float o1 = h0 * W2[(cb + 0) * 2 + 1] + h1_ * W2[(cb + 1) * 2 + 1]
             + h2_ * W2[(cb + 2) * 2 + 1] + h3 * W2[(cb + 3) * 2 + 1];
    o0 += __shfl_xor(o0, 1, 64); o0 += __shfl_xor(o0, 2, 64);
    o1 += __shfl_xor(o1, 1, 64); o1 += __shfl_xor(o1, 2, 64);
    if (c4 == 0)
        h2s[v] = pk2(o0 * dv, o1 * dv);   // pre-scaled, fp16x2
}

// ---------------------------------------------------------------- layer-2 gather + log_softmax
__global__ void gather2(const int* __restrict__ esrc, const int* __restrict__ row_start,
                        const int* __restrict__ cnt, const float* __restrict__ dis,
                        const unsigned* __restrict__ h2s, const float* __restrict__ b2,
                        float* __restrict__ out, int n, int nE) {
    int v = blockIdx.x * blockDim.x + threadIdx.x;
    if (v >= n) return;
    int beg = row_start[v], c = cnt[v];
    if (beg < 0) beg = 0;
    int end = beg + c;
    if (end > nE) end = nE;

    float a0 = 0.f, a1 = 0.f;
    for (int i = beg; i < end; ++i) {
        float2 f = up2(h2s[esrc[i]]);
        a0 += f.x; a1 += f.y;
    }
    float dv = dis[v];
    float2 self = up2(h2s[v]);
    float v0 = (a0 + self.x) * dv + b2[0];
    float v1 = (a1 + self.y) * dv + b2[1];
    float m = fmaxf(v0, v1);
    float lse = m + logf(expf(v0 - m) + expf(v1 - m));
    *(float2*)&out[(size_t)v * 2] = make_float2(v0 - lse, v1 - lse);
}

// ---------------------------------------------------------------- launch
extern "C" void kernel_launch(void* const* d_in, const int* in_sizes, int n_in,
                              void* d_out, int out_size, void* d_ws, size_t ws_size,
                              hipStream_t stream) {
    const float* x  = (const float*)d_in[0];
    const int*   ei = (const int*)d_in[1];   // int32 per harness contract
    const float* W1 = (const float*)d_in[2];
    const float* b1 = (const float*)d_in[3];
    const float* W2 = (const float*)d_in[4];
    const float* b2 = (const float*)d_in[5];
    float* out = (float*)d_out;

    int n  = in_sizes[0] / IN_DIM;   // 200000
    int nE = in_sizes[1] / 2;        // 6400000
    const int* src = ei;
    const int* dst = ei + nE;
    int NB = (n + (1 << BSHIFT) - 1) >> BSHIFT;   // 196 super-buckets

    char* ws = (char*)d_ws;
    size_t off = 0;
    auto take = [&](size_t bytes) {
        char* p = ws + off;
        off += (bytes + 255) & ~(size_t)255;
        return p;
    };
    int*      bucketCnt   = (int*)take((size_t)NB * 4);
    int*      bucketStart = (int*)take((size_t)NB * 4);
    int*      blockBase   = (int*)take((size_t)NBLK_A * NB * 4);   // 0.8 MB
    unsigned* packed      = (unsigned*)take((size_t)nE * 4);        // 25.6 MB
    int*      esrc        = (int*)take((size_t)nE * 4);             // 25.6 MB
    int*      cnt         = (int*)take((size_t)n * 4);
    int*      rowst       = (int*)take((size_t)n * 4);
    float*    dis         = (float*)take((size_t)n * 4);
    __half*   h1s         = (__half*)take((size_t)n * HID * 2);     // 6.4 MB fp16
    unsigned* h2s         = (unsigned*)take((size_t)n * 4);         // fp16x2
    (void)ws_size;   // ~62 MB total (ws >= 73 MB proven in round 6)

    int B = 256;
    int gN  = (n + B - 1) / B;
    int gN4 = (int)(((long long)n * 4 + B - 1) / B);

    zero_buckets<<<(NB + B - 1) / B, B, 0, stream>>>(bucketCnt, NB);
    binA_count<<<NBLK_A, B, 0, stream>>>(dst, bucketCnt, blockBase, nE, NB);
    bucket_scan<<<1, 64, 0, stream>>>(bucketCnt, bucketStart, NB);
    binA_scatter<<<NBLK_A, B, 0, stream>>>(src, dst, bucketStart, blockBase, packed, nE, NB);
    binB<<<NB, 1024, 0, stream>>>(packed, bucketStart, bucketCnt, esrc, cnt, rowst, dis, n, nE);
    xw1s_kernel<<<gN, B, 0, stream>>>(x, W1, dis, h1s, n);
    gather1<<<gN4, B, 0, stream>>>(esrc, rowst, cnt, dis, h1s, b1, W2, h2s, n, nE);
    gather2<<<gN, B, 0, stream>>>(esrc, rowst, cnt, dis, h2s, b2, out, n, nE);
}